// Round 1
// baseline (740.375 us; speedup 1.0000x reference)
//
#include <hip/hip_runtime.h>
#include <cstdint>
#include <cstddef>

typedef __attribute__((ext_vector_type(4))) float f32x4;
typedef __attribute__((ext_vector_type(8))) __bf16 bf16x8;
typedef __attribute__((ext_vector_type(8))) unsigned short u16x8;

__device__ __forceinline__ unsigned short f2bf(float f) {
  unsigned int u = __builtin_bit_cast(unsigned int, f);
  u = (u + 0x7FFFu + ((u >> 16) & 1u)) >> 16;
  return (unsigned short)u;
}
__device__ __forceinline__ float bf2f(unsigned short b) {
  return __builtin_bit_cast(float, ((unsigned int)b) << 16);
}

// async global->LDS, 16B per lane. LDS dest must be the wave-uniform base;
// HW writes lane l at base + l*16.
__device__ __forceinline__ void async_copy16(const void* g, void* l) {
  __builtin_amdgcn_global_load_lds(
      (__attribute__((address_space(1))) void*)(g),
      (__attribute__((address_space(3))) void*)(l), 16, 0, 0);
}

// ---------------------------------------------------------------------------
// C[m][n] = act(alpha * sum_k A[m][k] * Bt[n][k] + bias)
// BIAS_MODE: 0 none, 1 per-col (bias[n]), 2 per-row (bias[m])
// Tile 128x128, BK=64, 256 threads = 4 waves (2x2), each wave 64x64 (4x4 frags
// of 16x16x32 bf16 MFMA). LDS staged via global_load_lds with source-side XOR
// swizzle (slot ^= row&7) matched by the same XOR on ds_read_b128.
// All of M, N divisible by 128 and K by 64 in every use here (no bounds checks).
// ---------------------------------------------------------------------------
template <int BIAS_MODE, bool OUT_BF16>
__global__ __launch_bounds__(256) void gemm_bt(
    const unsigned short* __restrict__ A, const unsigned short* __restrict__ Bt,
    const float* __restrict__ bias, void* __restrict__ Cout,
    int M, int N, int K, int lda, int ldb, int ldc, float alpha)
{
  __shared__ unsigned short ldsbuf[2 * 128 * 64];  // 16KB A-tile + 16KB B-tile
  unsigned short* Alds = ldsbuf;
  unsigned short* Blds = ldsbuf + 128 * 64;

  const int tid  = threadIdx.x;
  const int wave = tid >> 6;
  const int lane = tid & 63;
  const int m0 = blockIdx.y * 128;
  const int n0 = blockIdx.x * 128;
  const int wm = (wave >> 1) * 64;
  const int wn = (wave & 1) * 64;

  const int srow  = tid >> 3;  // 0..31: row within a 32-row staging issue
  const int sslot = tid & 7;   // 0..7 : 16B slot within the 128B row

  const int quad = lane >> 4;  // 0..3
  const int l15  = lane & 15;

  f32x4 acc[4][4] = {};

  for (int kt = 0; kt < K; kt += 64) {
    // ---- stage A tile [128 rows][64 k] (4 issues x 4KB) ----
#pragma unroll
    for (int i = 0; i < 4; ++i) {
      int row = i * 32 + srow;
      int ls  = sslot ^ (row & 7);  // pre-swizzled global source
      async_copy16(A + (size_t)(m0 + row) * lda + kt + ls * 8,
                   (char*)Alds + i * 4096 + wave * 1024);
    }
    // ---- stage B tile [128 rows(n)][64 k] ----
#pragma unroll
    for (int i = 0; i < 4; ++i) {
      int row = i * 32 + srow;
      int ls  = sslot ^ (row & 7);
      async_copy16(Bt + (size_t)(n0 + row) * ldb + kt + ls * 8,
                   (char*)Blds + i * 4096 + wave * 1024);
    }
    __syncthreads();  // compiler drains vmcnt before s_barrier

#pragma unroll
    for (int kk = 0; kk < 2; ++kk) {
      bf16x8 af[4], bfr[4];
      const int lsl = kk * 4 + quad;  // logical 16B slot: k = lsl*8
#pragma unroll
      for (int i = 0; i < 4; ++i) {
        int ra = wm + i * 16 + l15;
        af[i] = *(const bf16x8*)((const char*)Alds + ra * 128 + ((lsl ^ (ra & 7)) * 16));
        int rb = wn + i * 16 + l15;
        bfr[i] = *(const bf16x8*)((const char*)Blds + rb * 128 + ((lsl ^ (rb & 7)) * 16));
      }
#pragma unroll
      for (int i = 0; i < 4; ++i)
#pragma unroll
        for (int j = 0; j < 4; ++j)
          acc[i][j] = __builtin_amdgcn_mfma_f32_16x16x32_bf16(af[i], bfr[j], acc[i][j], 0, 0, 0);
    }
    __syncthreads();  // protect LDS before next stage overwrites
  }

  // ---- epilogue: C/D frag layout col = lane&15, row = (lane>>4)*4 + reg ----
#pragma unroll
  for (int i = 0; i < 4; ++i) {
#pragma unroll
    for (int j = 0; j < 4; ++j) {
      const int rowb = m0 + wm + i * 16 + quad * 4;
      const int col  = n0 + wn + j * 16 + l15;
      float cb = 0.0f;
      if (BIAS_MODE == 1) cb = bias[col];
#pragma unroll
      for (int r = 0; r < 4; ++r) {
        float v = acc[i][j][r] * alpha + cb;
        if (BIAS_MODE == 2) v += bias[rowb + r];
        size_t idx = (size_t)(rowb + r) * ldc + col;
        if (OUT_BF16) ((unsigned short*)Cout)[idx] = f2bf(v);
        else          ((float*)Cout)[idx]          = v;
      }
    }
  }
}

// ---------------------------------------------------------------------------
// fp32 -> bf16 elementwise convert (vectorized float4 -> ushort4)
// ---------------------------------------------------------------------------
__global__ __launch_bounds__(256) void convert_f32_bf16(
    const float* __restrict__ x, unsigned short* __restrict__ y, int n4)
{
  int i = blockIdx.x * blockDim.x + threadIdx.x;
  const int stride = gridDim.x * blockDim.x;
  for (; i < n4; i += stride) {
    float4 v = ((const float4*)x)[i];
    ushort4 o;
    o.x = f2bf(v.x); o.y = f2bf(v.y); o.z = f2bf(v.z); o.w = f2bf(v.w);
    ((ushort4*)y)[i] = o;
  }
}

// ---------------------------------------------------------------------------
// W[1024][1024] fp32 -> WT[1024][1024] bf16 (transpose), 64x64 LDS tiles.
// blockIdx.z selects which of the three weight matrices.
// ---------------------------------------------------------------------------
__global__ __launch_bounds__(256) void transpose_to_bf16(
    const float* __restrict__ W0, const float* __restrict__ W1, const float* __restrict__ W2,
    unsigned short* __restrict__ T0, unsigned short* __restrict__ T1, unsigned short* __restrict__ T2)
{
  __shared__ float tile[64][65];
  const float* W = (blockIdx.z == 0) ? W0 : (blockIdx.z == 1) ? W1 : W2;
  unsigned short* T = (blockIdx.z == 0) ? T0 : (blockIdx.z == 1) ? T1 : T2;
  const int tx = threadIdx.x;  // 0..63
  const int ty = threadIdx.y;  // 0..3
  const int n0 = blockIdx.x * 64, k0 = blockIdx.y * 64;
#pragma unroll
  for (int r = ty; r < 64; r += 4)
    tile[r][tx] = W[(size_t)(k0 + r) * 1024 + n0 + tx];
  __syncthreads();
#pragma unroll
  for (int r = ty; r < 64; r += 4)
    T[(size_t)(n0 + r) * 1024 + k0 + tx] = f2bf(tile[tx][r]);
}

// ---------------------------------------------------------------------------
// In-place row softmax over bf16 rows of length 4096. One 256-thread block
// per row; 16 elements per thread (two b128 loads), block-wide max/sum.
// ---------------------------------------------------------------------------
__global__ __launch_bounds__(256) void softmax_rows(unsigned short* __restrict__ S, int ncols)
{
  __shared__ float red[8];
  unsigned short* p = S + (size_t)blockIdx.x * ncols;
  const int tid = threadIdx.x;

  u16x8 r0 = ((const u16x8*)p)[tid * 2];
  u16x8 r1 = ((const u16x8*)p)[tid * 2 + 1];
  float v[16];
#pragma unroll
  for (int i = 0; i < 8; ++i) v[i] = bf2f(r0[i]);
#pragma unroll
  for (int i = 0; i < 8; ++i) v[8 + i] = bf2f(r1[i]);

  float m = -1e30f;
#pragma unroll
  for (int i = 0; i < 16; ++i) m = fmaxf(m, v[i]);
#pragma unroll
  for (int off = 32; off; off >>= 1) m = fmaxf(m, __shfl_xor(m, off));
  if ((tid & 63) == 0) red[tid >> 6] = m;
  __syncthreads();
  m = fmaxf(fmaxf(red[0], red[1]), fmaxf(red[2], red[3]));

  float s = 0.0f;
#pragma unroll
  for (int i = 0; i < 16; ++i) {
    v[i] = exp2f((v[i] - m) * 1.44269504088896f);
    s += v[i];
  }
#pragma unroll
  for (int off = 32; off; off >>= 1) s += __shfl_xor(s, off);
  if ((tid & 63) == 0) red[4 + (tid >> 6)] = s;
  __syncthreads();
  s = red[4] + red[5] + red[6] + red[7];
  const float inv = 1.0f / s;

  u16x8 o0, o1;
#pragma unroll
  for (int i = 0; i < 8; ++i) o0[i] = f2bf(v[i] * inv);
#pragma unroll
  for (int i = 0; i < 8; ++i) o1[i] = f2bf(v[8 + i] * inv);
  ((u16x8*)p)[tid * 2] = o0;
  ((u16x8*)p)[tid * 2 + 1] = o1;
}

// ---------------------------------------------------------------------------
// Orchestration.
//   x:[4,4096,1024]f32  Wq,Wk,Wv:[1024,1024]f32  bq,bk,bv:[1024]f32
//   out: [4,4096,1024]f32
// Workspace layout (bytes):
//   Xb   @ 0          : 16384x1024 bf16  (33,554,432)
//   WqT  @ 33,554,432 : 1024x1024 bf16   ( 2,097,152)  WkT, WvT follow
//   Qb   @ 39,845,888 : 16384x1024 bf16
//   Kb   @ 73,400,320 : 16384x1024 bf16
//   VTb  @106,954,752 : 1024x16384 bf16  (V transposed: VT[h][b*4096+s])
//   Sb   @140,509,184 : 4096x4096 bf16   (per-batch scores, reused)
//   total ~166 MB
// ---------------------------------------------------------------------------
extern "C" void kernel_launch(void* const* d_in, const int* in_sizes, int n_in,
                              void* d_out, int out_size, void* d_ws, size_t ws_size,
                              hipStream_t stream) {
  (void)in_sizes; (void)n_in; (void)out_size; (void)ws_size;
  const float* x  = (const float*)d_in[0];
  const float* Wq = (const float*)d_in[1];
  const float* bq = (const float*)d_in[2];
  const float* Wk = (const float*)d_in[3];
  const float* bk = (const float*)d_in[4];
  const float* Wv = (const float*)d_in[5];
  const float* bv = (const float*)d_in[6];
  float* out = (float*)d_out;

  char* ws = (char*)d_ws;
  unsigned short* Xb  = (unsigned short*)(ws);
  unsigned short* WqT = (unsigned short*)(ws + 33554432);
  unsigned short* WkT = WqT + 1048576;
  unsigned short* WvT = WkT + 1048576;
  unsigned short* Qb  = (unsigned short*)(ws + 39845888);
  unsigned short* Kb  = (unsigned short*)(ws + 73400320);
  unsigned short* VTb = (unsigned short*)(ws + 106954752);
  unsigned short* Sb  = (unsigned short*)(ws + 140509184);

  // 1) precision conversion / weight transpose
  convert_f32_bf16<<<2048, 256, 0, stream>>>(x, Xb, 4194304);
  transpose_to_bf16<<<dim3(16, 16, 3), dim3(64, 4), 0, stream>>>(Wq, Wk, Wv, WqT, WkT, WvT);

  // 2) projections: Q = X*Wq + bq, K = X*Wk + bk (col-bias)
  gemm_bt<1, true><<<dim3(8, 128), 256, 0, stream>>>(Xb, WqT, bq, Qb,
      16384, 1024, 1024, 1024, 1024, 1024, 1.0f);
  gemm_bt<1, true><<<dim3(8, 128), 256, 0, stream>>>(Xb, WkT, bk, Kb,
      16384, 1024, 1024, 1024, 1024, 1024, 1.0f);
  //    VT[h][s] = sum_d WvT[h][d] X[s][d] + bv[h] (row-bias) -> V pre-transposed
  gemm_bt<2, true><<<dim3(128, 8), 256, 0, stream>>>(WvT, Xb, bv, VTb,
      1024, 16384, 1024, 1024, 1024, 16384, 1.0f);

  // 3) per-batch attention: S = Q K^T / 32 -> softmax -> O = P V
  for (int b = 0; b < 4; ++b) {
    const size_t qoff = (size_t)b * 4194304;  // b*4096*1024 elements
    gemm_bt<0, true><<<dim3(32, 32), 256, 0, stream>>>(Qb + qoff, Kb + qoff, nullptr, Sb,
        4096, 4096, 1024, 1024, 1024, 4096, 0.03125f);
    softmax_rows<<<4096, 256, 0, stream>>>(Sb, 4096);
    gemm_bt<0, false><<<dim3(8, 32), 256, 0, stream>>>(Sb, VTb + (size_t)b * 4096, nullptr, out + qoff,
        4096, 1024, 4096, 4096, 16384, 1024, 1.0f);
  }
}

// Round 2
// 452.367 us; speedup vs baseline: 1.6367x; 1.6367x over previous
//
#include <hip/hip_runtime.h>
#include <cstdint>
#include <cstddef>

typedef __attribute__((ext_vector_type(4))) float f32x4;
typedef __attribute__((ext_vector_type(8))) __bf16 bf16x8;
typedef __attribute__((ext_vector_type(8))) unsigned short u16x8;

__device__ __forceinline__ unsigned short f2bf(float f) {
  unsigned int u = __builtin_bit_cast(unsigned int, f);
  u = (u + 0x7FFFu + ((u >> 16) & 1u)) >> 16;
  return (unsigned short)u;
}
__device__ __forceinline__ float bf2f(unsigned short b) {
  return __builtin_bit_cast(float, ((unsigned int)b) << 16);
}

// async global->LDS, 16B/lane; LDS dest = wave-uniform base + lane*16.
__device__ __forceinline__ void async_copy16(const void* g, void* l) {
  __builtin_amdgcn_global_load_lds(
      (__attribute__((address_space(1))) void*)(g),
      (__attribute__((address_space(3))) void*)(l), 16, 0, 0);
}

// ---------------------------------------------------------------------------
// 256x256-tile, BK=64, 8-wave (2Mx4N), 8-phase counted-vmcnt GEMM (T2+T3+T4+T5).
// C[m][n] = alpha * sum_k A[m][k]*Bt[n][k] (+ bias).  BIAS_MODE: 0 none,
// 1 per-col, 2 per-row.  Grid: (N/256, M/256, Z) with element strides sAz/sBz/sCz.
// M%256==N%256==0, K%64==0, K>=128 in all uses here.
//
// LDS 128 KiB: buf{0,1} x (A[256][64] | B[256][64]) bf16, row stride 128 B.
// Swizzle: 16B-slot s XOR (row&7), applied on the *global source* address at
// staging (linear LDS dest, rule #21) and on the ds_read_b128 address. This
// measured SQ_LDS_BANK_CONFLICT == 0 in round 1.
//
// Phase schedule per K-tile t (quadrants (QM,QN)): p1(0,0) p2(0,1) p3(1,0)
// p4(1,1); 16 MFMA each. Prefetch deadness schedule:
//   p1: (t+1).A-qm1 -> idle buf     p2: (t+1).B-qn1 -> idle buf
//   p3: (t+2).A-qm0 -> LIVE buf (A-qm0 rows only read in p1/p2: dead)
//   p4: (t+2).B-qn0 -> LIVE buf (B-qn0 rows only read in p1/p3: dead)
// vmcnt(4) once per tile at p4 (the 4 newest = the (t+2) halves) guarantees
// tile t+1 fully landed; drain to 0 when t+2>=NT (tail).
// ---------------------------------------------------------------------------
template <int BIAS_MODE, bool OUT_BF16>
__global__ __launch_bounds__(512, 1) void gemm256(
    const unsigned short* __restrict__ A, const unsigned short* __restrict__ Bt,
    const float* __restrict__ bias, void* __restrict__ Cout,
    int K, int lda, int ldb, int ldc, float alpha,
    size_t sAz, size_t sBz, size_t sCz)
{
  __shared__ __align__(16) char lds[131072];

  const int tid = threadIdx.x;
  const int w = tid >> 6, lane = tid & 63;
  const int wm = w >> 2, wn = w & 3;
  const int l15 = lane & 15, q = lane >> 4, s7 = lane & 7;
  const int m0 = blockIdx.y * 256, n0 = blockIdx.x * 256;

  A  += (size_t)blockIdx.z * sAz;
  Bt += (size_t)blockIdx.z * sBz;

  // staging lane decomposition: 8 rows x 8 slots of 16B per wave-instruction
  const int srow = lane >> 3;          // 0..7
  const int sslot = s7 ^ srow;         // pre-swizzled global 16B slot
  const unsigned short* aS = A + (size_t)(m0 + srow) * lda + sslot * 8;
  const unsigned short* bS = Bt + (size_t)(n0 + srow) * ldb + sslot * 8;
  const int w8 = w * 8;                          // A chunk: rows H*64 + i2*128 + w*8
  const int rB0 = (w >> 2) * 64 + (w & 3) * 8;   // B chunk: rB0 + H*32 (+128)

  const int wmB = wm * 128, wnB = wn * 64;

#define LDSA(buf) (lds + (buf) * 65536)
#define LDSB(buf) (lds + (buf) * 65536 + 32768)

#define STAGE_A(H, kt, buf) do { \
    async_copy16(aS + (size_t)((H)*64 + w8) * lda + (kt),       LDSA(buf) + ((H)*64 + w8) * 128); \
    async_copy16(aS + (size_t)((H)*64 + 128 + w8) * lda + (kt), LDSA(buf) + ((H)*64 + 128 + w8) * 128); \
  } while (0)
#define STAGE_B(H, kt, buf) do { \
    async_copy16(bS + (size_t)(rB0 + (H)*32) * ldb + (kt),       LDSB(buf) + (rB0 + (H)*32) * 128); \
    async_copy16(bS + (size_t)(rB0 + (H)*32 + 128) * ldb + (kt), LDSB(buf) + (rB0 + (H)*32 + 128) * 128); \
  } while (0)

#define READ_A(QM) do { _Pragma("unroll") for (int i = 0; i < 4; ++i) { \
      const int ro = (wmB + (QM)*64 + i*16 + l15) * 128; \
      _Pragma("unroll") for (int kk = 0; kk < 2; ++kk) \
        afr[i][kk] = *(const bf16x8*)(Ab + ro + (((kk*4 + q) ^ s7) * 16)); } } while (0)
#define READ_B(QN) do { _Pragma("unroll") for (int j = 0; j < 2; ++j) { \
      const int ro = (wnB + (QN)*32 + j*16 + l15) * 128; \
      _Pragma("unroll") for (int kk = 0; kk < 2; ++kk) \
        bfr[j][kk] = *(const bf16x8*)(Bb + ro + (((kk*4 + q) ^ s7) * 16)); } } while (0)
#define MFMA_Q(MI0, NJ0) do { _Pragma("unroll") for (int i = 0; i < 4; ++i) \
      _Pragma("unroll") for (int j = 0; j < 2; ++j) \
      _Pragma("unroll") for (int kk = 0; kk < 2; ++kk) \
        acc[(MI0)+i][(NJ0)+j] = __builtin_amdgcn_mfma_f32_16x16x32_bf16( \
            afr[i][kk], bfr[j][kk], acc[(MI0)+i][(NJ0)+j], 0, 0, 0); } while (0)

  const int NT = K >> 6;
  f32x4 acc[8][4] = {};
  bf16x8 afr[4][2], bfr[2][2];

  // prologue: tile0 fully + tile1 {A-qm0, B-qn0}; wait tile0 (8 loads) landed
  STAGE_A(0, 0, 0); STAGE_A(1, 0, 0);
  STAGE_B(0, 0, 0); STAGE_B(1, 0, 0);
  if (NT > 1) {
    STAGE_A(0, 64, 1); STAGE_B(0, 64, 1);
    asm volatile("s_waitcnt vmcnt(4)" ::: "memory");
  } else {
    asm volatile("s_waitcnt vmcnt(0)" ::: "memory");
  }
  __builtin_amdgcn_s_barrier();

  for (int t = 0; t < NT; ++t) {
    const char* Ab = LDSA(t & 1);
    const char* Bb = LDSB(t & 1);
    const int kt1 = (t + 1) << 6, kt2 = (t + 2) << 6;
    const bool s1 = (t + 1 < NT), s2 = (t + 2 < NT);

    // phase 1 (QM=0, QN=0)
    READ_A(0); READ_B(0);
    if (s1) STAGE_A(1, kt1, (t + 1) & 1);
    __builtin_amdgcn_s_barrier();
    __builtin_amdgcn_s_setprio(1); MFMA_Q(0, 0); __builtin_amdgcn_s_setprio(0);
    __builtin_amdgcn_s_barrier();

    // phase 2 (0,1) — reuse afr
    READ_B(1);
    if (s1) STAGE_B(1, kt1, (t + 1) & 1);
    __builtin_amdgcn_s_barrier();
    __builtin_amdgcn_s_setprio(1); MFMA_Q(0, 2); __builtin_amdgcn_s_setprio(0);
    __builtin_amdgcn_s_barrier();

    // phase 3 (1,0)
    READ_A(1); READ_B(0);
    if (s2) STAGE_A(0, kt2, t & 1);      // overwrites A-qm0 (dead after p2)
    __builtin_amdgcn_s_barrier();
    __builtin_amdgcn_s_setprio(1); MFMA_Q(4, 0); __builtin_amdgcn_s_setprio(0);
    __builtin_amdgcn_s_barrier();

    // phase 4 (1,1)
    READ_B(1);
    if (s2) STAGE_B(0, kt2, t & 1);      // overwrites B-qn0 (dead after p3)
    __builtin_amdgcn_s_barrier();
    __builtin_amdgcn_s_setprio(1); MFMA_Q(4, 2); __builtin_amdgcn_s_setprio(0);
    if (s2) asm volatile("s_waitcnt vmcnt(4)" ::: "memory");  // tile t+1 landed
    else    asm volatile("s_waitcnt vmcnt(0)" ::: "memory");  // tail: drain all
    __builtin_amdgcn_s_barrier();
  }

  // epilogue: C/D frag layout col = lane&15, row = (lane>>4)*4 + reg
  char* Cb = (char*)Cout + (size_t)blockIdx.z * sCz * (OUT_BF16 ? 2 : 4);
#pragma unroll
  for (int mi = 0; mi < 8; ++mi) {
#pragma unroll
    for (int nj = 0; nj < 4; ++nj) {
      const int row0 = m0 + wmB + mi * 16 + q * 4;
      const int col  = n0 + wnB + nj * 16 + l15;
      float cb = (BIAS_MODE == 1) ? bias[col] : 0.0f;
#pragma unroll
      for (int r = 0; r < 4; ++r) {
        float v = acc[mi][nj][r] * alpha + cb;
        if (BIAS_MODE == 2) v += bias[row0 + r];
        const size_t idx = (size_t)(row0 + r) * ldc + col;
        if (OUT_BF16) ((unsigned short*)Cb)[idx] = f2bf(v);
        else          ((float*)Cb)[idx] = v;
      }
    }
  }
#undef LDSA
#undef LDSB
#undef STAGE_A
#undef STAGE_B
#undef READ_A
#undef READ_B
#undef MFMA_Q
}

// ---------------------------------------------------------------------------
// fp32 -> bf16 elementwise convert
// ---------------------------------------------------------------------------
__global__ __launch_bounds__(256) void convert_f32_bf16(
    const float* __restrict__ x, unsigned short* __restrict__ y, int n4)
{
  int i = blockIdx.x * blockDim.x + threadIdx.x;
  const int stride = gridDim.x * blockDim.x;
  for (; i < n4; i += stride) {
    float4 v = ((const float4*)x)[i];
    ushort4 o;
    o.x = f2bf(v.x); o.y = f2bf(v.y); o.z = f2bf(v.z); o.w = f2bf(v.w);
    ((ushort4*)y)[i] = o;
  }
}

// ---------------------------------------------------------------------------
// W[1024][1024] fp32 -> WT[1024][1024] bf16 (transpose)
// ---------------------------------------------------------------------------
__global__ __launch_bounds__(256) void transpose_to_bf16(
    const float* __restrict__ W0, const float* __restrict__ W1, const float* __restrict__ W2,
    unsigned short* __restrict__ T0, unsigned short* __restrict__ T1, unsigned short* __restrict__ T2)
{
  __shared__ float tile[64][65];
  const float* W = (blockIdx.z == 0) ? W0 : (blockIdx.z == 1) ? W1 : W2;
  unsigned short* T = (blockIdx.z == 0) ? T0 : (blockIdx.z == 1) ? T1 : T2;
  const int tx = threadIdx.x;  // 0..63
  const int ty = threadIdx.y;  // 0..3
  const int n0 = blockIdx.x * 64, k0 = blockIdx.y * 64;
#pragma unroll
  for (int r = ty; r < 64; r += 4)
    tile[r][tx] = W[(size_t)(k0 + r) * 1024 + n0 + tx];
  __syncthreads();
#pragma unroll
  for (int r = ty; r < 64; r += 4)
    T[(size_t)(n0 + r) * 1024 + k0 + tx] = f2bf(tile[tx][r]);
}

// ---------------------------------------------------------------------------
// In-place row softmax over bf16 rows of length 4096 (1 block / row)
// ---------------------------------------------------------------------------
__global__ __launch_bounds__(256) void softmax_rows(unsigned short* __restrict__ S, int ncols)
{
  __shared__ float red[8];
  unsigned short* p = S + (size_t)blockIdx.x * ncols;
  const int tid = threadIdx.x;

  u16x8 r0 = ((const u16x8*)p)[tid * 2];
  u16x8 r1 = ((const u16x8*)p)[tid * 2 + 1];
  float v[16];
#pragma unroll
  for (int i = 0; i < 8; ++i) v[i] = bf2f(r0[i]);
#pragma unroll
  for (int i = 0; i < 8; ++i) v[8 + i] = bf2f(r1[i]);

  float m = -1e30f;
#pragma unroll
  for (int i = 0; i < 16; ++i) m = fmaxf(m, v[i]);
#pragma unroll
  for (int off = 32; off; off >>= 1) m = fmaxf(m, __shfl_xor(m, off));
  if ((tid & 63) == 0) red[tid >> 6] = m;
  __syncthreads();
  m = fmaxf(fmaxf(red[0], red[1]), fmaxf(red[2], red[3]));

  float s = 0.0f;
#pragma unroll
  for (int i = 0; i < 16; ++i) {
    v[i] = exp2f((v[i] - m) * 1.44269504088896f);
    s += v[i];
  }
#pragma unroll
  for (int off = 32; off; off >>= 1) s += __shfl_xor(s, off);
  if ((tid & 63) == 0) red[4 + (tid >> 6)] = s;
  __syncthreads();
  s = red[4] + red[5] + red[6] + red[7];
  const float inv = 1.0f / s;

  u16x8 o0, o1;
#pragma unroll
  for (int i = 0; i < 8; ++i) o0[i] = f2bf(v[i] * inv);
#pragma unroll
  for (int i = 0; i < 8; ++i) o1[i] = f2bf(v[8 + i] * inv);
  ((u16x8*)p)[tid * 2] = o0;
  ((u16x8*)p)[tid * 2 + 1] = o1;
}

// ---------------------------------------------------------------------------
// Orchestration. x:[4,4096,1024]f32, W*:[1024,1024]f32, b*:[1024]f32,
// out:[4,4096,1024]f32.
//
// Batched path (ws >= 224 MB): S for all 4 batches lives in ws; one PV
// dispatch with grid (4,16,4) = 256 blocks (full GPU).
//   WT @0 (6.29MB) and Xb @6291456 (32MB) both sit INSIDE the S_all region
//   (dead after projections). S_all @0 (128MB), Qb @134217728, Kb @167772160,
//   VTb @201326592; total 234,881,024 B.
// Fallback (ws >= 174,063,616 B — proven by round 1): per-batch S (32MB),
//   per-batch PV at 64 blocks.
//   WT @0, Qb @6291456, Kb @39845888, VTb @73400320, Xb @106954752,
//   Sb @140509184.
// ---------------------------------------------------------------------------
extern "C" void kernel_launch(void* const* d_in, const int* in_sizes, int n_in,
                              void* d_out, int out_size, void* d_ws, size_t ws_size,
                              hipStream_t stream) {
  (void)in_sizes; (void)n_in; (void)out_size;
  const float* x  = (const float*)d_in[0];
  const float* Wq = (const float*)d_in[1];
  const float* bq = (const float*)d_in[2];
  const float* Wk = (const float*)d_in[3];
  const float* bk = (const float*)d_in[4];
  const float* Wv = (const float*)d_in[5];
  const float* bv = (const float*)d_in[6];
  float* out = (float*)d_out;
  char* ws = (char*)d_ws;

  const bool batched = ws_size >= 234881024ull;

  unsigned short *WqT, *WkT, *WvT, *Xb, *Qb, *Kb, *VTb, *Sall = nullptr, *Sb = nullptr;
  if (batched) {
    WqT = (unsigned short*)(ws);
    WkT = WqT + 1048576; WvT = WkT + 1048576;
    Xb  = (unsigned short*)(ws + 6291456);
    Sall = (unsigned short*)(ws);
    Qb  = (unsigned short*)(ws + 134217728);
    Kb  = (unsigned short*)(ws + 167772160);
    VTb = (unsigned short*)(ws + 201326592);
  } else {
    WqT = (unsigned short*)(ws);
    WkT = WqT + 1048576; WvT = WkT + 1048576;
    Qb  = (unsigned short*)(ws + 6291456);
    Kb  = (unsigned short*)(ws + 39845888);
    VTb = (unsigned short*)(ws + 73400320);
    Xb  = (unsigned short*)(ws + 106954752);
    Sb  = (unsigned short*)(ws + 140509184);
  }

  // 1) precision conversion / weight transpose
  convert_f32_bf16<<<2048, 256, 0, stream>>>(x, Xb, 4194304);
  transpose_to_bf16<<<dim3(16, 16, 3), dim3(64, 4), 0, stream>>>(Wq, Wk, Wv, WqT, WkT, WvT);

  // 2) projections (K=1024): Q,K col-bias; V produced pre-transposed, row-bias
  gemm256<1, true><<<dim3(4, 64, 1), 512, 0, stream>>>(Xb, WqT, bq, Qb,
      1024, 1024, 1024, 1024, 1.0f, 0, 0, 0);
  gemm256<1, true><<<dim3(4, 64, 1), 512, 0, stream>>>(Xb, WkT, bk, Kb,
      1024, 1024, 1024, 1024, 1.0f, 0, 0, 0);
  gemm256<2, true><<<dim3(64, 4, 1), 512, 0, stream>>>(WvT, Xb, bv, VTb,
      1024, 1024, 1024, 16384, 1.0f, 0, 0, 0);

  if (batched) {
    // 3) S = Q K^T / 32 for all batches (1024 blocks)
    gemm256<0, true><<<dim3(16, 16, 4), 512, 0, stream>>>(Qb, Kb, nullptr, Sall,
        1024, 1024, 1024, 4096, 0.03125f, 4194304, 4194304, 16777216);
    // 4) softmax over all 16384 rows
    softmax_rows<<<16384, 256, 0, stream>>>(Sall, 4096);
    // 5) O = P V, all batches in one 256-block dispatch
    gemm256<0, false><<<dim3(4, 16, 4), 512, 0, stream>>>(Sall, VTb, nullptr, out,
        4096, 4096, 16384, 1024, 1.0f, 16777216, 4096, 4194304);
  } else {
    for (int b = 0; b < 4; ++b) {
      const size_t qoff = (size_t)b * 4194304;
      gemm256<0, true><<<dim3(16, 16, 1), 512, 0, stream>>>(Qb + qoff, Kb + qoff, nullptr, Sb,
          1024, 1024, 1024, 4096, 0.03125f, 0, 0, 0);
      softmax_rows<<<4096, 256, 0, stream>>>(Sb, 4096);
      gemm256<0, false><<<dim3(4, 16, 1), 512, 0, stream>>>(Sb, VTb + (size_t)b * 4096, nullptr, out + qoff,
          4096, 4096, 16384, 1024, 1.0f, 0, 0, 0);
    }
  }
}

// Round 3
// 443.234 us; speedup vs baseline: 1.6704x; 1.0206x over previous
//
#include <hip/hip_runtime.h>
#include <cstdint>
#include <cstddef>

typedef __attribute__((ext_vector_type(4))) float f32x4;
typedef __attribute__((ext_vector_type(8))) __bf16 bf16x8;
typedef __attribute__((ext_vector_type(8))) unsigned short u16x8;

__device__ __forceinline__ unsigned short f2bf(float f) {
  unsigned int u = __builtin_bit_cast(unsigned int, f);
  u = (u + 0x7FFFu + ((u >> 16) & 1u)) >> 16;
  return (unsigned short)u;
}
__device__ __forceinline__ float bf2f(unsigned short b) {
  return __builtin_bit_cast(float, ((unsigned int)b) << 16);
}

// async global->LDS, 16B/lane; LDS dest = wave-uniform base + lane*16.
__device__ __forceinline__ void async_copy16(const void* g, void* l) {
  __builtin_amdgcn_global_load_lds(
      (__attribute__((address_space(1))) void*)(g),
      (__attribute__((address_space(3))) void*)(l), 16, 0, 0);
}

// ---------------------------------------------------------------------------
// 256x256-tile, BK=64, 8-wave (2Mx4N), 4-phase counted-vmcnt GEMM.
// C[m][n] = alpha * sum_k A[m][k]*Bt[n][k] (+ bias). BIAS_MODE: 0 none,
// 1 per-col (bias[z*sbiasz + n]), 2 per-row. Grid (N/256, M/256, Z), element
// strides sAz/sBz/sCz. M%256==N%256==0, K%64==0, K>=192.
//
// LDS 128 KiB: buf{0,1} x (A[256][64] | B[256][64]) bf16, row stride 128B.
// Swizzle: 16B-slot s XOR (row&7) on the *global source* at staging (linear
// LDS dest, rule #21) and on the ds_read_b128 address (round-1: 0 conflicts).
//
// Per-tile phase schedule (16 MFMA each; B register-resident all tile,
// A-quadrant resident 2 phases -> 24 ds_read_b128/wave/tile):
//   p1: read B-q0,A-q0,B-q1 (16);      stage A-chunk1(t+1) -> idle buf
//   p2: (no reads, MFMA from regs);    stage B-chunk1(t+1) -> idle buf
//   p3: read A-q1 (8, overwrite afr);  stage A-chunk0(t+2) -> LIVE buf
//   p4: (no reads);                    stage B-chunk0(t+2) -> LIVE buf
// Deadness (exact): block-level A-chunk0 rows {0-63,128-191} are only read
// in p1 (wm=0 waves rows 0-63, wm=1 rows 128-191); B-chunk0 rows
// {0-31,64-95,128-159,192-223} only in p1. Stages into the live buffer are
// issued >=1 full barrier pair after the last reader.
// vmcnt(4) once per tile at p4: 12 outstanding -> completes the 8 oldest =
// all four halves of tile t+1. Tail (t+2>=NT): drain to 0.
// ---------------------------------------------------------------------------
template <int BIAS_MODE, bool OUT_BF16>
__global__ __launch_bounds__(512, 1) void gemm256(
    const unsigned short* __restrict__ A, const unsigned short* __restrict__ Bt,
    const float* __restrict__ bias, void* __restrict__ Cout,
    int K, int lda, int ldb, int ldc, float alpha,
    size_t sAz, size_t sBz, size_t sCz, size_t sbiasz)
{
  __shared__ __align__(16) char lds[131072];

  const int tid = threadIdx.x;
  const int w = tid >> 6, lane = tid & 63;
  const int wm = w >> 2, wn = w & 3;
  const int l15 = lane & 15, q = lane >> 4, s7 = lane & 7;
  const int m0 = blockIdx.y * 256, n0 = blockIdx.x * 256;

  A  += (size_t)blockIdx.z * sAz;
  Bt += (size_t)blockIdx.z * sBz;
  if (BIAS_MODE) bias += (size_t)blockIdx.z * sbiasz;

  // staging: each instr covers 8 rows x 8 swizzled 16B slots
  const int srow = lane >> 3;
  const int sslot = s7 ^ srow;  // pre-swizzled global 16B slot
  const unsigned short* aS = A + (size_t)(m0 + srow) * lda + sslot * 8;
  const unsigned short* bS = Bt + (size_t)(n0 + srow) * ldb + sslot * 8;
  const int arb = (w >> 2) * 128 + (w & 3) * 16;  // A: + c*64 + {0,8}
  const int brb = (w >> 1) * 64 + (w & 1) * 16;   // B: + c*32 + {0,8}

  const int wmB = wm * 128, wnB = wn * 64;

#define LDSA(buf) (lds + (buf) * 65536)
#define LDSB(buf) (lds + (buf) * 65536 + 32768)

#define STAGE_A(c, kt, buf) do { \
    async_copy16(aS + (size_t)(arb + (c)*64) * lda + (kt),     LDSA(buf) + (arb + (c)*64) * 128); \
    async_copy16(aS + (size_t)(arb + (c)*64 + 8) * lda + (kt), LDSA(buf) + (arb + (c)*64 + 8) * 128); \
  } while (0)
#define STAGE_B(c, kt, buf) do { \
    async_copy16(bS + (size_t)(brb + (c)*32) * ldb + (kt),     LDSB(buf) + (brb + (c)*32) * 128); \
    async_copy16(bS + (size_t)(brb + (c)*32 + 8) * ldb + (kt), LDSB(buf) + (brb + (c)*32 + 8) * 128); \
  } while (0)

#define READ_A(QM) do { _Pragma("unroll") for (int i = 0; i < 4; ++i) { \
      const int ro = (wmB + (QM)*64 + i*16 + l15) * 128; \
      _Pragma("unroll") for (int kk = 0; kk < 2; ++kk) \
        afr[i][kk] = *(const bf16x8*)(Ab + ro + (((kk*4 + q) ^ s7) * 16)); } } while (0)
#define READ_B(QN) do { _Pragma("unroll") for (int j = 0; j < 2; ++j) { \
      const int ro = (wnB + (QN)*32 + j*16 + l15) * 128; \
      _Pragma("unroll") for (int kk = 0; kk < 2; ++kk) \
        bfr[(QN)*2 + j][kk] = *(const bf16x8*)(Bb + ro + (((kk*4 + q) ^ s7) * 16)); } } while (0)
#define MFMA_Q(QM, QN) do { _Pragma("unroll") for (int i = 0; i < 4; ++i) \
      _Pragma("unroll") for (int j = 0; j < 2; ++j) \
      _Pragma("unroll") for (int kk = 0; kk < 2; ++kk) \
        acc[(QM)*4+i][(QN)*2+j] = __builtin_amdgcn_mfma_f32_16x16x32_bf16( \
            afr[i][kk], bfr[(QN)*2+j][kk], acc[(QM)*4+i][(QN)*2+j], 0, 0, 0); } while (0)

  const int NT = K >> 6;
  f32x4 acc[8][4] = {};
  bf16x8 afr[4][2];   // current A quadrant (overwritten in p3)
  bf16x8 bfr[4][2];   // ALL of B, resident across the whole tile

  // prologue: tile0 fully + tile1 {A-chunk0, B-chunk0} into buf1
  STAGE_A(0, 0, 0); STAGE_A(1, 0, 0);
  STAGE_B(0, 0, 0); STAGE_B(1, 0, 0);
  STAGE_A(0, 64, 1); STAGE_B(0, 64, 1);
  asm volatile("s_waitcnt vmcnt(4)" ::: "memory");  // tile0's 8 landed
  __builtin_amdgcn_s_barrier();

  for (int t = 0; t < NT; ++t) {
    const char* Ab = LDSA(t & 1);
    const char* Bb = LDSB(t & 1);
    const int kt1 = (t + 1) << 6, kt2 = (t + 2) << 6;
    const bool s1 = (t + 1 < NT), s2 = (t + 2 < NT);

    // p1 (0,0)
    READ_B(0); READ_A(0); READ_B(1);
    if (s1) STAGE_A(1, kt1, (t + 1) & 1);
    __builtin_amdgcn_s_barrier();
    __builtin_amdgcn_s_setprio(1); MFMA_Q(0, 0); __builtin_amdgcn_s_setprio(0);
    __builtin_amdgcn_s_barrier();

    // p2 (0,1) — pure register MFMA
    if (s1) STAGE_B(1, kt1, (t + 1) & 1);
    __builtin_amdgcn_s_barrier();
    __builtin_amdgcn_s_setprio(1); MFMA_Q(0, 1); __builtin_amdgcn_s_setprio(0);
    __builtin_amdgcn_s_barrier();

    // p3 (1,0)
    READ_A(1);
    if (s2) STAGE_A(0, kt2, t & 1);   // A-chunk0 dead after p1
    __builtin_amdgcn_s_barrier();
    __builtin_amdgcn_s_setprio(1); MFMA_Q(1, 0); __builtin_amdgcn_s_setprio(0);
    __builtin_amdgcn_s_barrier();

    // p4 (1,1)
    if (s2) STAGE_B(0, kt2, t & 1);   // B-chunk0 dead after p1
    __builtin_amdgcn_s_barrier();
    __builtin_amdgcn_s_setprio(1); MFMA_Q(1, 1); __builtin_amdgcn_s_setprio(0);
    if (s2) asm volatile("s_waitcnt vmcnt(4)" ::: "memory");  // tile t+1 landed
    else    asm volatile("s_waitcnt vmcnt(0)" ::: "memory");  // tail drain
    __builtin_amdgcn_s_barrier();
  }

  // epilogue: C/D frag layout col = lane&15, row = (lane>>4)*4 + reg
  char* Cb = (char*)Cout + (size_t)blockIdx.z * sCz * (OUT_BF16 ? 2 : 4);
#pragma unroll
  for (int mi = 0; mi < 8; ++mi) {
#pragma unroll
    for (int nj = 0; nj < 4; ++nj) {
      const int row0 = m0 + wmB + mi * 16 + q * 4;
      const int col  = n0 + wnB + nj * 16 + l15;
      float cb = (BIAS_MODE == 1) ? bias[col] : 0.0f;
#pragma unroll
      for (int r = 0; r < 4; ++r) {
        float v = acc[mi][nj][r] * alpha + cb;
        if (BIAS_MODE == 2) v += bias[row0 + r];
        const size_t idx = (size_t)(row0 + r) * ldc + col;
        if (OUT_BF16) ((unsigned short*)Cb)[idx] = f2bf(v);
        else          ((float*)Cb)[idx] = v;
      }
    }
  }
#undef LDSA
#undef LDSB
#undef STAGE_A
#undef STAGE_B
#undef READ_A
#undef READ_B
#undef MFMA_Q
}

// ---------------------------------------------------------------------------
// fp32 -> bf16 elementwise convert
// ---------------------------------------------------------------------------
__global__ __launch_bounds__(256) void convert_f32_bf16(
    const float* __restrict__ x, unsigned short* __restrict__ y, int n4)
{
  int i = blockIdx.x * blockDim.x + threadIdx.x;
  const int stride = gridDim.x * blockDim.x;
  for (; i < n4; i += stride) {
    float4 v = ((const float4*)x)[i];
    ushort4 o;
    o.x = f2bf(v.x); o.y = f2bf(v.y); o.z = f2bf(v.z); o.w = f2bf(v.w);
    ((ushort4*)y)[i] = o;
  }
}

// ---------------------------------------------------------------------------
// W[1024][1024] fp32 -> WT[1024][1024] bf16 (transpose)
// ---------------------------------------------------------------------------
__global__ __launch_bounds__(256) void transpose_to_bf16(
    const float* __restrict__ W0, const float* __restrict__ W1, const float* __restrict__ W2,
    unsigned short* __restrict__ T0, unsigned short* __restrict__ T1, unsigned short* __restrict__ T2)
{
  __shared__ float tile[64][65];
  const float* W = (blockIdx.z == 0) ? W0 : (blockIdx.z == 1) ? W1 : W2;
  unsigned short* T = (blockIdx.z == 0) ? T0 : (blockIdx.z == 1) ? T1 : T2;
  const int tx = threadIdx.x;  // 0..63
  const int ty = threadIdx.y;  // 0..3
  const int n0 = blockIdx.x * 64, k0 = blockIdx.y * 64;
#pragma unroll
  for (int r = ty; r < 64; r += 4)
    tile[r][tx] = W[(size_t)(k0 + r) * 1024 + n0 + tx];
  __syncthreads();
#pragma unroll
  for (int r = ty; r < 64; r += 4)
    T[(size_t)(n0 + r) * 1024 + k0 + tx] = f2bf(tile[tx][r]);
}

// ---------------------------------------------------------------------------
// In-place row softmax over bf16 rows of length 4096 (1 block / row)
// ---------------------------------------------------------------------------
__global__ __launch_bounds__(256) void softmax_rows(unsigned short* __restrict__ S, int ncols)
{
  __shared__ float red[8];
  unsigned short* p = S + (size_t)blockIdx.x * ncols;
  const int tid = threadIdx.x;

  u16x8 r0 = ((const u16x8*)p)[tid * 2];
  u16x8 r1 = ((const u16x8*)p)[tid * 2 + 1];
  float v[16];
#pragma unroll
  for (int i = 0; i < 8; ++i) v[i] = bf2f(r0[i]);
#pragma unroll
  for (int i = 0; i < 8; ++i) v[8 + i] = bf2f(r1[i]);

  float m = -1e30f;
#pragma unroll
  for (int i = 0; i < 16; ++i) m = fmaxf(m, v[i]);
#pragma unroll
  for (int off = 32; off; off >>= 1) m = fmaxf(m, __shfl_xor(m, off));
  if ((tid & 63) == 0) red[tid >> 6] = m;
  __syncthreads();
  m = fmaxf(fmaxf(red[0], red[1]), fmaxf(red[2], red[3]));

  float s = 0.0f;
#pragma unroll
  for (int i = 0; i < 16; ++i) {
    v[i] = exp2f((v[i] - m) * 1.44269504088896f);
    s += v[i];
  }
#pragma unroll
  for (int off = 32; off; off >>= 1) s += __shfl_xor(s, off);
  if ((tid & 63) == 0) red[4 + (tid >> 6)] = s;
  __syncthreads();
  s = red[4] + red[5] + red[6] + red[7];
  const float inv = 1.0f / s;

  u16x8 o0, o1;
#pragma unroll
  for (int i = 0; i < 8; ++i) o0[i] = f2bf(v[i] * inv);
#pragma unroll
  for (int i = 0; i < 8; ++i) o1[i] = f2bf(v[8 + i] * inv);
  ((u16x8*)p)[tid * 2] = o0;
  ((u16x8*)p)[tid * 2 + 1] = o1;
}

// ---------------------------------------------------------------------------
// Orchestration. x:[4,4096,1024]f32, W*:[1024,1024]f32, b*:[1024]f32,
// out:[4,4096,1024]f32.
//
// Batched path (ws >= 224 MB):
//   WT @0 (6.29MB) and Xb @6291456 (32MB) sit INSIDE the S_all region (dead
//   after projections). biasQK (8KB f32[2][1024]) @39845888 (also inside).
//   S_all @0 (128MB), Qb @134217728, Kb @167772160 (contig: sCz=16777216
//   elem), VTb @201326592; total 234,881,024 B.
// Fallback (ws >= 174,063,616 B): per-batch S; separate Q/K projections.
// ---------------------------------------------------------------------------
extern "C" void kernel_launch(void* const* d_in, const int* in_sizes, int n_in,
                              void* d_out, int out_size, void* d_ws, size_t ws_size,
                              hipStream_t stream) {
  (void)in_sizes; (void)n_in; (void)out_size;
  const float* x  = (const float*)d_in[0];
  const float* Wq = (const float*)d_in[1];
  const float* bq = (const float*)d_in[2];
  const float* Wk = (const float*)d_in[3];
  const float* bk = (const float*)d_in[4];
  const float* Wv = (const float*)d_in[5];
  const float* bv = (const float*)d_in[6];
  float* out = (float*)d_out;
  char* ws = (char*)d_ws;

  const bool batched = ws_size >= 234881024ull;

  unsigned short *WqT, *WkT, *WvT, *Xb, *Qb, *Kb, *VTb, *Sall = nullptr, *Sb = nullptr;
  float* biasQK = nullptr;
  if (batched) {
    WqT = (unsigned short*)(ws);
    WkT = WqT + 1048576; WvT = WkT + 1048576;
    Xb  = (unsigned short*)(ws + 6291456);
    biasQK = (float*)(ws + 39845888);
    Sall = (unsigned short*)(ws);
    Qb  = (unsigned short*)(ws + 134217728);
    Kb  = (unsigned short*)(ws + 167772160);
    VTb = (unsigned short*)(ws + 201326592);
  } else {
    WqT = (unsigned short*)(ws);
    WkT = WqT + 1048576; WvT = WkT + 1048576;
    Qb  = (unsigned short*)(ws + 6291456);
    Kb  = (unsigned short*)(ws + 39845888);
    VTb = (unsigned short*)(ws + 73400320);
    Xb  = (unsigned short*)(ws + 106954752);
    Sb  = (unsigned short*)(ws + 140509184);
  }

  // 1) precision conversion / weight transpose
  convert_f32_bf16<<<2048, 256, 0, stream>>>(x, Xb, 4194304);
  transpose_to_bf16<<<dim3(16, 16, 3), dim3(64, 4), 0, stream>>>(Wq, Wk, Wv, WqT, WkT, WvT);

  // 2) projections (K=1024)
  if (batched) {
    hipMemcpyAsync(biasQK,        bq, 4096, hipMemcpyDeviceToDevice, stream);
    hipMemcpyAsync(biasQK + 1024, bk, 4096, hipMemcpyDeviceToDevice, stream);
    // fused Q,K projection: z picks {Wq->Qb, Wk->Kb}, 512 blocks
    gemm256<1, true><<<dim3(4, 64, 2), 512, 0, stream>>>(Xb, WqT, biasQK, Qb,
        1024, 1024, 1024, 1024, 1.0f, 0, 1048576, 16777216, 1024);
  } else {
    gemm256<1, true><<<dim3(4, 64, 1), 512, 0, stream>>>(Xb, WqT, bq, Qb,
        1024, 1024, 1024, 1024, 1.0f, 0, 0, 0, 0);
    gemm256<1, true><<<dim3(4, 64, 1), 512, 0, stream>>>(Xb, WkT, bk, Kb,
        1024, 1024, 1024, 1024, 1.0f, 0, 0, 0, 0);
  }
  // V pre-transposed: VT[h][s] = sum_d WvT[h][d] X[s][d] + bv[h] (row-bias)
  gemm256<2, true><<<dim3(64, 4, 1), 512, 0, stream>>>(WvT, Xb, bv, VTb,
      1024, 1024, 1024, 16384, 1.0f, 0, 0, 0, 0);

  if (batched) {
    // 3) S = Q K^T / 32, all batches (1024 blocks)
    gemm256<0, true><<<dim3(16, 16, 4), 512, 0, stream>>>(Qb, Kb, nullptr, Sall,
        1024, 1024, 1024, 4096, 0.03125f, 4194304, 4194304, 16777216, 0);
    // 4) softmax over all 16384 rows
    softmax_rows<<<16384, 256, 0, stream>>>(Sall, 4096);
    // 5) O = P V, all batches (256 blocks)
    gemm256<0, false><<<dim3(4, 16, 4), 512, 0, stream>>>(Sall, VTb, nullptr, out,
        4096, 4096, 16384, 1024, 1.0f, 16777216, 4096, 4194304, 0);
  } else {
    for (int b = 0; b < 4; ++b) {
      const size_t qoff = (size_t)b * 4194304;
      gemm256<0, true><<<dim3(16, 16, 1), 512, 0, stream>>>(Qb + qoff, Kb + qoff, nullptr, Sb,
          1024, 1024, 1024, 4096, 0.03125f, 0, 0, 0, 0);
      softmax_rows<<<4096, 256, 0, stream>>>(Sb, 4096);
      gemm256<0, false><<<dim3(4, 16, 1), 512, 0, stream>>>(Sb, VTb + (size_t)b * 4096, nullptr, out + qoff,
          4096, 4096, 16384, 1024, 1.0f, 0, 0, 0, 0);
    }
  }
}